// Round 2
// baseline (318.015 us; speedup 1.0000x reference)
//
#include <hip/hip_runtime.h>

// CPPN fused forward: 12 -> 32 -> 32 -> 32 -> 3, per-node activation select.
// P = 1M pixels, f32 in/out. Compute-bound on vector f32 FMAs (~34us roofline);
// weights staged in LDS (broadcast reads), 2 pixels/thread so each b128 weight
// read feeds 8 FMAs.

#define BLK 256
#define PIX 2

constexpr int NIN = 12, HID = 32, NOUT = 3;

__device__ __forceinline__ float tanh_fast(float x) {
    // tanh(x) = 1 - 2/(exp(2x)+1); exact limits at +-inf, ~2e-6 abs error.
    float e = __expf(2.0f * x);
    return 1.0f - 2.0f * __builtin_amdgcn_rcpf(e + 1.0f);
}

__device__ __forceinline__ float apply_act(float x, int id_in) {
    // id is identical across the wave (node index is compile-time); force scalar
    // so the switch is wave-uniform (no divergence).
    int id = __builtin_amdgcn_readfirstlane(id_in);
    switch (id) {
        case 1: return tanh_fast(x);
        case 2: { float e = __expf(-x); return __builtin_amdgcn_rcpf(1.0f + e); }
        case 3: return __sinf(x);
        case 4: return __expf(-0.5f * x * x);
        default: return x;  // 0 = identity
    }
}

template <int NI>
__device__ __forceinline__ void layer(const float (&hin)[PIX][HID],
                                      float (&hout)[PIX][HID],
                                      const float* __restrict__ sW,
                                      const float* __restrict__ sb,
                                      const int* __restrict__ sa) {
#pragma unroll
    for (int jb = 0; jb < HID / 4; ++jb) {
        const float4 bb = *reinterpret_cast<const float4*>(sb + jb * 4);
        float4 acc[PIX];
#pragma unroll
        for (int p = 0; p < PIX; ++p) acc[p] = bb;
#pragma unroll
        for (int i = 0; i < NI; ++i) {
            // wave-uniform address -> LDS broadcast, conflict-free
            const float4 w = *reinterpret_cast<const float4*>(sW + i * HID + jb * 4);
#pragma unroll
            for (int p = 0; p < PIX; ++p) {
                acc[p].x = fmaf(hin[p][i], w.x, acc[p].x);
                acc[p].y = fmaf(hin[p][i], w.y, acc[p].y);
                acc[p].z = fmaf(hin[p][i], w.z, acc[p].z);
                acc[p].w = fmaf(hin[p][i], w.w, acc[p].w);
            }
        }
#pragma unroll
        for (int p = 0; p < PIX; ++p) {
            hout[p][jb * 4 + 0] = apply_act(acc[p].x, sa[jb * 4 + 0]);
            hout[p][jb * 4 + 1] = apply_act(acc[p].y, sa[jb * 4 + 1]);
            hout[p][jb * 4 + 2] = apply_act(acc[p].z, sa[jb * 4 + 2]);
            hout[p][jb * 4 + 3] = apply_act(acc[p].w, sa[jb * 4 + 3]);
        }
    }
}

__global__ void __launch_bounds__(BLK) cppn_kernel(
    const float* __restrict__ xin, const float* __restrict__ bin,
    const float* __restrict__ W1, const float* __restrict__ b1, const int* __restrict__ a1,
    const float* __restrict__ W2, const float* __restrict__ b2, const int* __restrict__ a2,
    const float* __restrict__ W3, const float* __restrict__ b3, const int* __restrict__ a3,
    const float* __restrict__ Wo, const float* __restrict__ bo,
    float* __restrict__ out, int Ppix) {
    __shared__ alignas(16) float sW1[NIN * HID];
    __shared__ alignas(16) float sW2[HID * HID];
    __shared__ alignas(16) float sW3[HID * HID];
    __shared__ alignas(16) float sWo[HID * NOUT];
    __shared__ alignas(16) float sb1[HID];
    __shared__ alignas(16) float sb2[HID];
    __shared__ alignas(16) float sb3[HID];
    __shared__ alignas(16) float sbin[16];
    __shared__ alignas(16) float sbo[4];
    __shared__ int sa1[HID], sa2[HID], sa3[HID];

    const int t = threadIdx.x;
    for (int i = t; i < NIN * HID; i += BLK) sW1[i] = W1[i];
    for (int i = t; i < HID * HID; i += BLK) sW2[i] = W2[i];
    for (int i = t; i < HID * HID; i += BLK) sW3[i] = W3[i];
    if (t < HID * NOUT) sWo[t] = Wo[t];
    if (t < HID) {
        sb1[t] = b1[t]; sb2[t] = b2[t]; sb3[t] = b3[t];
        sa1[t] = a1[t]; sa2[t] = a2[t]; sa3[t] = a3[t];
    }
    if (t < NIN) sbin[t] = bin[t];
    if (t < NOUT) sbo[t] = bo[t];
    __syncthreads();

    const long long base = (long long)blockIdx.x * (BLK * PIX) + t;

    float A[PIX][HID];
    float B[PIX][HID];

    // h0 = inputs + bias_in  (held in A[p][0..11])
#pragma unroll
    for (int p = 0; p < PIX; ++p) {
        const long long px = base + (long long)p * BLK;
        if (px < Ppix) {
            const float4* ip = reinterpret_cast<const float4*>(xin + px * NIN);
            const float4 x0 = ip[0], x1 = ip[1], x2 = ip[2];
            const float xv[NIN] = {x0.x, x0.y, x0.z, x0.w,
                                   x1.x, x1.y, x1.z, x1.w,
                                   x2.x, x2.y, x2.z, x2.w};
#pragma unroll
            for (int i = 0; i < NIN; ++i) A[p][i] = xv[i] + sbin[i];
        } else {
#pragma unroll
            for (int i = 0; i < NIN; ++i) A[p][i] = 0.0f;
        }
    }

    layer<NIN>(A, B, sW1, sb1, sa1);   // h1
    layer<HID>(B, A, sW2, sb2, sa2);   // h2
    layer<HID>(A, B, sW3, sb3, sa3);   // h3

    // output: tanh(h3 @ Wout + bout)
#pragma unroll
    for (int p = 0; p < PIX; ++p) {
        const long long px = base + (long long)p * BLK;
        if (px >= Ppix) continue;
        float o[NOUT];
#pragma unroll
        for (int c = 0; c < NOUT; ++c) {
            float acc = sbo[c];
#pragma unroll
            for (int i = 0; i < HID; ++i) acc = fmaf(B[p][i], sWo[i * NOUT + c], acc);
            o[c] = tanh_fast(acc);
        }
        out[px * 3 + 0] = o[0];
        out[px * 3 + 1] = o[1];
        out[px * 3 + 2] = o[2];
    }
}

extern "C" void kernel_launch(void* const* d_in, const int* in_sizes, int n_in,
                              void* d_out, int out_size, void* d_ws, size_t ws_size,
                              hipStream_t stream) {
    (void)n_in; (void)out_size; (void)d_ws; (void)ws_size;
    const float* xin = (const float*)d_in[0];
    const float* bin = (const float*)d_in[1];
    const float* W1  = (const float*)d_in[2];
    const float* b1  = (const float*)d_in[3];
    const int*   a1  = (const int*)  d_in[4];
    const float* W2  = (const float*)d_in[5];
    const float* b2  = (const float*)d_in[6];
    const int*   a2  = (const int*)  d_in[7];
    const float* W3  = (const float*)d_in[8];
    const float* b3  = (const float*)d_in[9];
    const int*   a3  = (const int*)  d_in[10];
    const float* Wo  = (const float*)d_in[11];
    const float* bo  = (const float*)d_in[12];
    float* out = (float*)d_out;

    const int Ppix = in_sizes[0] / NIN;
    const int grid = (Ppix + BLK * PIX - 1) / (BLK * PIX);
    hipLaunchKernelGGL(cppn_kernel, dim3(grid), dim3(BLK), 0, stream,
                       xin, bin, W1, b1, a1, W2, b2, a2, W3, b3, a3, Wo, bo,
                       out, Ppix);
}